// Round 1
// baseline (4075.047 us; speedup 1.0000x reference)
//
#include <hip/hip_runtime.h>
#include <hip/hip_bf16.h>
#include <math.h>

// SNN forward: 64 -> 1024 -> 1024 -> 10, T=4000, B=16, LIF beta=exp(-0.025),
// thr=1, hard reset to 0, Dale clamp W>=0.
// Strategy: layer-phased. Per time-chunk: GEMM (spikes @ W-limbs, bf16x2 MFMA,
// fp32 acc) -> scan kernel (per-(b,j) fp64 LIF chain over t). Spike matrices
// stored as bf16 {0,1} (exact) and fed to the next layer's GEMM.

#define T_STEPS 4000
#define NB 16
#define N_IN 64
#define NH 1024
#define N_OUT 10

typedef __attribute__((ext_vector_type(8))) short bf16x8;
typedef __attribute__((ext_vector_type(4))) float f32x4;
typedef __hip_bfloat16 bf16;

// ---------------- small utility kernels ----------------

__global__ void k_zero(double* p, int n) {
    int i = blockIdx.x * 256 + threadIdx.x;
    if (i < n) p[i] = 0.0;
}

__global__ void k_cvt(const float* __restrict__ in, bf16* __restrict__ out, int n) {
    int i = blockIdx.x * 256 + threadIdx.x;
    if (i < n) out[i] = __float2bfloat16(in[i]);   // 0.0/1.0 -> exact
}

// Build BT[n][k2] (row-major [Npad x 2K]) from W [K x N] row-major:
//   k2 <  K : hi limb of max(W[k2][n],0)
//   k2 >= K : lo limb (w - float(hi))
//   n >= N  : 0 (padding columns)
__global__ void k_limbs(const float* __restrict__ W, bf16* __restrict__ BT,
                        int K, int N, int Npad) {
    int idx = blockIdx.x * 256 + threadIdx.x;
    int total = Npad * 2 * K;
    if (idx >= total) return;
    int n  = idx / (2 * K);
    int k2 = idx - n * (2 * K);
    float v = 0.f;
    if (n < N) {
        int k = (k2 < K) ? k2 : k2 - K;
        float w = fmaxf(W[(size_t)k * N + n], 0.f);      // Dale's law clamp
        float hi = __bfloat162float(__float2bfloat16(w));
        v = (k2 < K) ? w : (w - hi);
    }
    BT[idx] = __float2bfloat16(v);
}

// ---------------- GEMM: C[M x Npad] = A[M x KA] @ BT^T, bf16 inputs, f32 out
// A logical K = K2 (limb-duplicated): A column k maps to k & (KA-1).
// BT is [Npad x K2] (i.e. B transposed), so both tiles load as [128 rows x 64 k].
// m97-style 128x128 tile, BK=64, 4 waves (2x2), 4x4 16x16x32 frags per wave.

__global__ __launch_bounds__(256) void k_gemm(
    const bf16* __restrict__ A, const bf16* __restrict__ BT,
    float* __restrict__ C, int KA, int K2, int Npad) {
    __shared__ __align__(16) short Alds[128 * 64];
    __shared__ __align__(16) short Blds[128 * 64];
    const int m0 = blockIdx.x * 128;
    const int n0 = blockIdx.y * 128;
    const int tid  = threadIdx.x;
    const int lane = tid & 63;
    const int wave = tid >> 6;
    const int wm = (wave >> 1) * 64;      // wave's M offset in tile
    const int wn = (wave & 1) * 64;       // wave's N offset in tile
    const int r16 = lane & 15;            // frag row (A) / col (B,D)
    const int kg  = lane >> 4;            // k-group 0..3
    f32x4 acc[4][4] = {};
    const int kmask = KA - 1;
    const int nkt = K2 >> 6;
    for (int kt = 0; kt < nkt; ++kt) {
        const int kA0 = (kt << 6) & kmask;
        const int kB0 = kt << 6;
        __syncthreads();
        // stage both tiles: 1024 x 16B each, 4 rounds x 256 threads
#pragma unroll
        for (int r = 0; r < 4; ++r) {
            int idx = r * 256 + tid;      // 16B unit within tile
            int row = idx >> 3;           // 8 x 16B = one 64-elem bf16 row
            int c8  = (idx & 7) << 3;     // element offset in row
            *(bf16x8*)&Alds[row * 64 + c8] =
                *(const bf16x8*)&A[(size_t)(m0 + row) * KA + kA0 + c8];
            *(bf16x8*)&Blds[row * 64 + c8] =
                *(const bf16x8*)&BT[(size_t)(n0 + row) * K2 + kB0 + c8];
        }
        __syncthreads();
#pragma unroll
        for (int kk = 0; kk < 2; ++kk) {
            bf16x8 af[4], bfr[4];
#pragma unroll
            for (int i = 0; i < 4; ++i) {
                af[i]  = *(const bf16x8*)&Alds[(wm + i * 16 + r16) * 64 + kk * 32 + kg * 8];
                bfr[i] = *(const bf16x8*)&Blds[(wn + i * 16 + r16) * 64 + kk * 32 + kg * 8];
            }
#pragma unroll
            for (int mi = 0; mi < 4; ++mi)
#pragma unroll
                for (int ni = 0; ni < 4; ++ni)
                    acc[mi][ni] = __builtin_amdgcn_mfma_f32_16x16x32_bf16(
                        af[mi], bfr[ni], acc[mi][ni], 0, 0, 0);
        }
    }
    // epilogue: D row = kg*4 + r, col = r16 (verified m89 mapping)
#pragma unroll
    for (int mi = 0; mi < 4; ++mi)
#pragma unroll
        for (int ni = 0; ni < 4; ++ni)
#pragma unroll
            for (int r = 0; r < 4; ++r) {
                int row = m0 + wm + mi * 16 + kg * 4 + r;
                int col = n0 + wn + ni * 16 + r16;
                C[(size_t)row * Npad + col] = acc[mi][ni][r];
            }
}

// ---------------- LIF scan kernels (fp64 membranes) ----------------

// hidden layer: 16384 threads, thread gid = b*1024 + j
__global__ void k_scan_hidden(const float* __restrict__ I, const float* __restrict__ bias,
                              double* __restrict__ mstate, bf16* __restrict__ S,
                              int Tc, double beta) {
    int gid = blockIdx.x * 256 + threadIdx.x;
    int j = gid & (NH - 1);
    int b = gid >> 10;
    double m = mstate[gid];
    float bj = bias[j];
    const bf16 one  = __float2bfloat16(1.0f);
    const bf16 zero = __float2bfloat16(0.0f);
    for (int t = 0; t < Tc; ++t) {
        size_t off = ((size_t)t * NB + b) * NH + j;
        float Iv = I[off] + bj;
        m = beta * m + (double)Iv;
        bool sp = (m >= 1.0);
        S[off] = sp ? one : zero;
        m = sp ? 0.0 : m;
    }
    mstate[gid] = m;
}

// output layer: one block of 256 threads, gid = b*16 + k (k<10 live)
__global__ void k_scan_out(const float* __restrict__ I2, const float* __restrict__ bias,
                           double* __restrict__ mstate, float* __restrict__ out,
                           int Tc, int t0, double beta) {
    int gid = threadIdx.x;
    int k = gid & 15;
    int b = gid >> 4;
    double m = mstate[gid];
    float bk = (k < N_OUT) ? bias[k] : 0.f;
    for (int t = 0; t < Tc; ++t) {
        float Iv = I2[((size_t)t * NB + b) * 128 + k] + bk;
        m = beta * m + (double)Iv;
        bool sp = (m >= 1.0);
        if (k < N_OUT) out[((size_t)(t0 + t) * NB + b) * N_OUT + k] = sp ? 1.f : 0.f;
        m = sp ? 0.0 : m;
    }
    mstate[gid] = m;
}

// ---------------- host ----------------

extern "C" void kernel_launch(void* const* d_in, const int* in_sizes, int n_in,
                              void* d_out, int out_size, void* d_ws, size_t ws_size,
                              hipStream_t stream) {
    const float* in_sp = (const float*)d_in[0];
    const float* W0 = (const float*)d_in[1];
    const float* b0 = (const float*)d_in[2];
    const float* W1 = (const float*)d_in[3];
    const float* b1 = (const float*)d_in[4];
    const float* W2 = (const float*)d_in[5];
    const float* b2 = (const float*)d_in[6];
    float* out = (float*)d_out;

    char* p = (char*)d_ws;
    auto carve = [&](size_t bytes) -> void* {
        char* r = p; p += (bytes + 255) & ~(size_t)255; return (void*)r;
    };
    bf16* A_in = (bf16*)carve((size_t)T_STEPS * NB * N_IN * 2);
    bf16* BT0  = (bf16*)carve((size_t)NH * 2 * N_IN * 2);
    bf16* BT1  = (bf16*)carve((size_t)NH * 2 * NH * 2);
    bf16* BT2  = (bf16*)carve((size_t)128 * 2 * NH * 2);
    double* m0s = (double*)carve((size_t)NB * NH * 8);
    double* m1s = (double*)carve((size_t)NB * NH * 8);
    double* m2s = (double*)carve((size_t)NB * 16 * 8);
    size_t fixed = (size_t)(p - (char*)d_ws);

    // choose time-chunk (Mc must be /128, Tc must divide 4000 and be /8)
    const int tc_opts[4] = {2000, 1000, 200, 40};
    int Tc = 40;
    for (int i = 0; i < 4; ++i) {
        size_t Mc_ = (size_t)tc_opts[i] * NB;
        size_t need = fixed
            + ((Mc_ * NH * 4 + 255) & ~(size_t)255)
            + ((Mc_ * 128 * 4 + 255) & ~(size_t)255)
            + 2 * ((Mc_ * NH * 2 + 255) & ~(size_t)255);
        if (need <= ws_size) { Tc = tc_opts[i]; break; }
    }
    size_t Mc = (size_t)Tc * NB;
    float* IBUF  = (float*)carve(Mc * NH * 4);
    float* I2BUF = (float*)carve(Mc * 128 * 4);
    bf16*  S0    = (bf16*)carve(Mc * NH * 2);
    bf16*  S1    = (bf16*)carve(Mc * NH * 2);

    const double beta = exp(-0.25 / 10.0);

    // init membrane states (every call: harness does not re-poison)
    int nM = NB * NH;
    k_zero<<<(nM + 255) / 256, 256, 0, stream>>>(m0s, nM);
    k_zero<<<(nM + 255) / 256, 256, 0, stream>>>(m1s, nM);
    k_zero<<<1, 256, 0, stream>>>(m2s, NB * 16);

    int nIn = T_STEPS * NB * N_IN;
    k_cvt<<<(nIn + 255) / 256, 256, 0, stream>>>(in_sp, A_in, nIn);

    k_limbs<<<(NH * 2 * N_IN + 255) / 256, 256, 0, stream>>>(W0, BT0, N_IN, NH, NH);
    k_limbs<<<(NH * 2 * NH + 255) / 256, 256, 0, stream>>>(W1, BT1, NH, NH, NH);
    k_limbs<<<(128 * 2 * NH + 255) / 256, 256, 0, stream>>>(W2, BT2, NH, N_OUT, 128);

    const int C = T_STEPS / Tc;
    for (int c = 0; c < C; ++c) {
        int t0 = c * Tc;
        const bf16* Ain_c = A_in + (size_t)t0 * NB * N_IN;
        dim3 g0((unsigned)(Mc / 128), NH / 128);
        dim3 g2((unsigned)(Mc / 128), 1);
        // layer 0
        k_gemm<<<g0, 256, 0, stream>>>(Ain_c, BT0, IBUF, N_IN, 2 * N_IN, NH);
        k_scan_hidden<<<(NB * NH) / 256, 256, 0, stream>>>(IBUF, b0, m0s, S0, Tc, beta);
        // layer 1
        k_gemm<<<g0, 256, 0, stream>>>(S0, BT1, IBUF, NH, 2 * NH, NH);
        k_scan_hidden<<<(NB * NH) / 256, 256, 0, stream>>>(IBUF, b1, m1s, S1, Tc, beta);
        // layer 2 (N padded to 128)
        k_gemm<<<g2, 256, 0, stream>>>(S1, BT2, I2BUF, NH, 2 * NH, 128);
        k_scan_out<<<1, 256, 0, stream>>>(I2BUF, b2, m2s, out, Tc, t0, beta);
    }
}

// Round 2
// 1703.673 us; speedup vs baseline: 2.3919x; 2.3919x over previous
//
#include <hip/hip_runtime.h>
#include <hip/hip_bf16.h>
#include <math.h>

// SNN forward: 64 -> 1024 -> 1024 -> 10, T=4000, B=16, LIF beta=exp(-0.025),
// thr=1, hard reset to 0, Dale clamp W>=0.
// Layer-phased: per time-chunk, GEMM (spikes @ W bf16-limbs, fp32 acc) ->
// LIF scan (fp64 membranes, prefetch-pipelined loads). Spikes as bf16 {0,1}.

#define T_STEPS 4000
#define NB 16
#define N_IN 64
#define NH 1024
#define N_OUT 10

typedef __attribute__((ext_vector_type(8))) short bf16x8;
typedef __attribute__((ext_vector_type(4))) float f32x4;
typedef __hip_bfloat16 bf16;

#define ASG(p) (const __attribute__((address_space(1))) void*)(p)
#define ASL(p) (__attribute__((address_space(3))) void*)(p)

// ---------------- small utility kernels ----------------

__global__ void k_zero(double* p, int n) {
    int i = blockIdx.x * 256 + threadIdx.x;
    if (i < n) p[i] = 0.0;
}

__global__ void k_cvt(const float* __restrict__ in, bf16* __restrict__ out, int n) {
    int i = blockIdx.x * 256 + threadIdx.x;
    if (i < n) out[i] = __float2bfloat16(in[i]);   // 0.0/1.0 -> exact
}

// Build BT[n][k2] (row-major [Npad x 2K]) from W [K x N] row-major:
//   k2 < K: hi limb of max(W,0); k2 >= K: lo limb (w - hi); n >= N: 0.
__global__ void k_limbs(const float* __restrict__ W, bf16* __restrict__ BT,
                        int K, int N, int Npad) {
    int idx = blockIdx.x * 256 + threadIdx.x;
    int total = Npad * 2 * K;
    if (idx >= total) return;
    int n  = idx / (2 * K);
    int k2 = idx - n * (2 * K);
    float v = 0.f;
    if (n < N) {
        int k = (k2 < K) ? k2 : k2 - K;
        float w = fmaxf(W[(size_t)k * N + n], 0.f);      // Dale's law clamp
        float hi = __bfloat162float(__float2bfloat16(w));
        v = (k2 < K) ? w : (w - hi);
    }
    BT[idx] = __float2bfloat16(v);
}

// ---------------- GEMM: C[M x ldc] = A[M x KA] @ BT^T, bf16 in, f32 out ----
// A logical K = K2 (limb-duplicated): A column k maps to k & (KA-1).
// BT is [Npad x K2]. 128x128 tile, BK=64, 4 waves (2x2), 4x4 16x16x32 frags.
// Staging via global_load_lds width=16 (linear LDS layout, per-lane gaddr).
// Store only cols < ldc (compact C for the thin output layer).

__global__ __launch_bounds__(256) void k_gemm(
    const bf16* __restrict__ A, const bf16* __restrict__ BT,
    float* __restrict__ C, int KA, int K2, int ldc) {
    __shared__ __align__(16) short Alds[128 * 64];
    __shared__ __align__(16) short Blds[128 * 64];
    const int m0 = blockIdx.x * 128;
    const int n0 = blockIdx.y * 128;
    const int tid  = threadIdx.x;
    const int lane = tid & 63;
    const int wave = tid >> 6;
    const int wbase = wave * 64;          // lane-uniform within wave
    const int wm = (wave >> 1) * 64;
    const int wn = (wave & 1) * 64;
    const int r16 = lane & 15;
    const int kg  = lane >> 4;
    f32x4 acc[4][4] = {};
    const int kmask = KA - 1;
    const int nkt = K2 >> 6;
    for (int kt = 0; kt < nkt; ++kt) {
        const int kA0 = (kt << 6) & kmask;
        const int kB0 = kt << 6;
        __syncthreads();
        // stage both tiles: 1024 x 16B each; global_load_lds, 16B/lane
#pragma unroll
        for (int r = 0; r < 4; ++r) {
            int idx = r * 256 + wbase + lane;   // 16B unit within tile
            int row = idx >> 3;
            int c8  = (idx & 7) << 3;
            __builtin_amdgcn_global_load_lds(
                ASG(&A[(size_t)(m0 + row) * KA + kA0 + c8]),
                ASL(&Alds[(r * 256 + wbase) * 8]), 16, 0, 0);
            __builtin_amdgcn_global_load_lds(
                ASG(&BT[(size_t)(n0 + row) * K2 + kB0 + c8]),
                ASL(&Blds[(r * 256 + wbase) * 8]), 16, 0, 0);
        }
        __syncthreads();
#pragma unroll
        for (int kk = 0; kk < 2; ++kk) {
            bf16x8 af[4], bfr[4];
#pragma unroll
            for (int i = 0; i < 4; ++i) {
                af[i]  = *(const bf16x8*)&Alds[(wm + i * 16 + r16) * 64 + kk * 32 + kg * 8];
                bfr[i] = *(const bf16x8*)&Blds[(wn + i * 16 + r16) * 64 + kk * 32 + kg * 8];
            }
#pragma unroll
            for (int mi = 0; mi < 4; ++mi)
#pragma unroll
                for (int ni = 0; ni < 4; ++ni)
                    acc[mi][ni] = __builtin_amdgcn_mfma_f32_16x16x32_bf16(
                        af[mi], bfr[ni], acc[mi][ni], 0, 0, 0);
        }
    }
    // epilogue: D row = kg*4 + r, col = r16 (m89 mapping); store cols < ldc
#pragma unroll
    for (int mi = 0; mi < 4; ++mi)
#pragma unroll
        for (int ni = 0; ni < 4; ++ni) {
            int col = n0 + wn + ni * 16 + r16;
            if (col < ldc) {
#pragma unroll
                for (int r = 0; r < 4; ++r) {
                    int row = m0 + wm + mi * 16 + kg * 4 + r;
                    C[(size_t)row * ldc + col] = acc[mi][ni][r];
                }
            }
        }
}

// ---------------- LIF scan kernels (fp64 membranes, pipelined loads) -------

#define LIF_STEP(OFF, V)                                        \
    {                                                           \
        m = beta * m + (double)((V) + bj);                      \
        bool sp = (m >= 1.0);                                   \
        S[OFF] = sp ? one : zero;                               \
        m = sp ? 0.0 : m;                                       \
    }

// hidden layer: 16384 chains, 64-thread blocks (1 wave) x 256 blocks
__global__ __launch_bounds__(64) void k_scan_hidden(
    const float* __restrict__ I, const float* __restrict__ bias,
    double* __restrict__ mstate, bf16* __restrict__ S, int Tc, double beta) {
    int gid = blockIdx.x * 64 + threadIdx.x;
    int j = gid & (NH - 1);
    double m = mstate[gid];
    float bj = bias[j];
    const bf16 one  = __float2bfloat16(1.0f);
    const bf16 zero = __float2bfloat16(0.0f);
    const size_t stride = (size_t)NB * NH;       // per-t stride
    const float* Ip = I + gid;                   // I[t*stride + gid_layout]
    // gid layout: gid = b*NH + j and I rows are (t*NB+b)*NH + j = t*stride + gid
    float bufA[8], bufB[8];
#pragma unroll
    for (int u = 0; u < 8; ++u) bufA[u] = Ip[(size_t)u * stride];
    for (int tb = 0; tb < Tc; tb += 16) {
#pragma unroll
        for (int u = 0; u < 8; ++u) bufB[u] = Ip[(size_t)(tb + 8 + u) * stride];
#pragma unroll
        for (int u = 0; u < 8; ++u) {
            size_t off = (size_t)(tb + u) * stride + gid;
            LIF_STEP(off, bufA[u]);
        }
        if (tb + 16 < Tc) {
#pragma unroll
            for (int u = 0; u < 8; ++u) bufA[u] = Ip[(size_t)(tb + 16 + u) * stride];
        }
#pragma unroll
        for (int u = 0; u < 8; ++u) {
            size_t off = (size_t)(tb + 8 + u) * stride + gid;
            LIF_STEP(off, bufB[u]);
        }
    }
    mstate[gid] = m;
}

// output layer: 256 chains (160 live), compact I2 [Mc x 16]
__global__ __launch_bounds__(256) void k_scan_out(
    const float* __restrict__ I2, const float* __restrict__ bias,
    double* __restrict__ mstate, float* __restrict__ out,
    int Tc, int t0, double beta) {
    int gid = threadIdx.x;
    int k = gid & 15;
    int b = gid >> 4;
    double m = mstate[gid];
    float bj = (k < N_OUT) ? bias[k] : 0.f;
    const float* Ip = I2 + gid;                  // I2[t*256 + gid]
    float bufA[8], bufB[8];
#pragma unroll
    for (int u = 0; u < 8; ++u) bufA[u] = Ip[(size_t)u * 256];
    for (int tb = 0; tb < Tc; tb += 16) {
#pragma unroll
        for (int u = 0; u < 8; ++u) bufB[u] = Ip[(size_t)(tb + 8 + u) * 256];
#pragma unroll
        for (int u = 0; u < 8; ++u) {
            int t = tb + u;
            m = beta * m + (double)(bufA[u] + bj);
            bool sp = (m >= 1.0);
            if (k < N_OUT) out[((size_t)(t0 + t) * NB + b) * N_OUT + k] = sp ? 1.f : 0.f;
            m = sp ? 0.0 : m;
        }
        if (tb + 16 < Tc) {
#pragma unroll
            for (int u = 0; u < 8; ++u) bufA[u] = Ip[(size_t)(tb + 16 + u) * 256];
        }
#pragma unroll
        for (int u = 0; u < 8; ++u) {
            int t = tb + 8 + u;
            m = beta * m + (double)(bufB[u] + bj);
            bool sp = (m >= 1.0);
            if (k < N_OUT) out[((size_t)(t0 + t) * NB + b) * N_OUT + k] = sp ? 1.f : 0.f;
            m = sp ? 0.0 : m;
        }
    }
    mstate[gid] = m;
}

// ---------------- host ----------------

extern "C" void kernel_launch(void* const* d_in, const int* in_sizes, int n_in,
                              void* d_out, int out_size, void* d_ws, size_t ws_size,
                              hipStream_t stream) {
    const float* in_sp = (const float*)d_in[0];
    const float* W0 = (const float*)d_in[1];
    const float* b0 = (const float*)d_in[2];
    const float* W1 = (const float*)d_in[3];
    const float* b1 = (const float*)d_in[4];
    const float* W2 = (const float*)d_in[5];
    const float* b2 = (const float*)d_in[6];
    float* out = (float*)d_out;

    char* p = (char*)d_ws;
    auto carve = [&](size_t bytes) -> void* {
        char* r = p; p += (bytes + 255) & ~(size_t)255; return (void*)r;
    };
    bf16* A_in = (bf16*)carve((size_t)T_STEPS * NB * N_IN * 2);
    bf16* BT0  = (bf16*)carve((size_t)NH * 2 * N_IN * 2);
    bf16* BT1  = (bf16*)carve((size_t)NH * 2 * NH * 2);
    bf16* BT2  = (bf16*)carve((size_t)128 * 2 * NH * 2);
    double* m0s = (double*)carve((size_t)NB * NH * 8);
    double* m1s = (double*)carve((size_t)NB * NH * 8);
    double* m2s = (double*)carve((size_t)NB * 16 * 8);
    size_t fixed = (size_t)(p - (char*)d_ws);

    // time-chunk: Tc | 4000, Tc % 16 == 0 (scan pipeline), Mc % 128 == 0
    const int tc_opts[4] = {2000, 400, 80, 16};
    int Tc = 16;
    for (int i = 0; i < 4; ++i) {
        size_t Mc_ = (size_t)tc_opts[i] * NB;
        size_t need = fixed
            + ((Mc_ * NH * 4 + 255) & ~(size_t)255)
            + ((Mc_ * 16 * 4 + 255) & ~(size_t)255)
            + 2 * ((Mc_ * NH * 2 + 255) & ~(size_t)255);
        if (need <= ws_size) { Tc = tc_opts[i]; break; }
    }
    size_t Mc = (size_t)Tc * NB;
    float* IBUF  = (float*)carve(Mc * NH * 4);
    float* I2BUF = (float*)carve(Mc * 16 * 4);
    bf16*  S0    = (bf16*)carve(Mc * NH * 2);
    bf16*  S1    = (bf16*)carve(Mc * NH * 2);

    const double beta = exp(-0.25 / 10.0);

    int nM = NB * NH;
    k_zero<<<(nM + 255) / 256, 256, 0, stream>>>(m0s, nM);
    k_zero<<<(nM + 255) / 256, 256, 0, stream>>>(m1s, nM);
    k_zero<<<1, 256, 0, stream>>>(m2s, NB * 16);

    int nIn = T_STEPS * NB * N_IN;
    k_cvt<<<(nIn + 255) / 256, 256, 0, stream>>>(in_sp, A_in, nIn);

    k_limbs<<<(NH * 2 * N_IN + 255) / 256, 256, 0, stream>>>(W0, BT0, N_IN, NH, NH);
    k_limbs<<<(NH * 2 * NH + 255) / 256, 256, 0, stream>>>(W1, BT1, NH, NH, NH);
    k_limbs<<<(128 * 2 * NH + 255) / 256, 256, 0, stream>>>(W2, BT2, NH, N_OUT, 128);

    const int C = T_STEPS / Tc;
    for (int c = 0; c < C; ++c) {
        int t0 = c * Tc;
        const bf16* Ain_c = A_in + (size_t)t0 * NB * N_IN;
        dim3 g0((unsigned)(Mc / 128), NH / 128);
        dim3 g2((unsigned)(Mc / 128), 1);
        // layer 0
        k_gemm<<<g0, 256, 0, stream>>>(Ain_c, BT0, IBUF, N_IN, 2 * N_IN, NH);
        k_scan_hidden<<<(NB * NH) / 64, 64, 0, stream>>>(IBUF, b0, m0s, S0, Tc, beta);
        // layer 1
        k_gemm<<<g0, 256, 0, stream>>>(S0, BT1, IBUF, NH, 2 * NH, NH);
        k_scan_hidden<<<(NB * NH) / 64, 64, 0, stream>>>(IBUF, b1, m1s, S1, Tc, beta);
        // layer 2 (compact 16-col C)
        k_gemm<<<g2, 256, 0, stream>>>(S1, BT2, I2BUF, NH, 2 * NH, 16);
        k_scan_out<<<1, 256, 0, stream>>>(I2BUF, b2, m2s, out, Tc, t0, beta);
    }
}

// Round 3
// 1128.222 us; speedup vs baseline: 3.6119x; 1.5101x over previous
//
#include <hip/hip_runtime.h>
#include <hip/hip_bf16.h>
#include <math.h>

// SNN forward: 64 -> 1024 -> 1024 -> 10, T=4000, B=16, LIF beta=exp(-0.025),
// thr=1, hard reset to 0, Dale clamp W>=0.
// Layer-phased: per time-chunk, GEMM (spikes @ W bf16-limbs, fp32 acc) ->
// LIF scan (fp64 membranes, prefetch-pipelined loads). Spikes as bf16 {0,1}.
// BT is limb-interleaved ([hi64|lo64] per source k-block) so each A k-tile
// serves two consecutive GEMM k-iterations (A staged once per pair).

#define T_STEPS 4000
#define NB 16
#define N_IN 64
#define NH 1024
#define N_OUT 10

typedef __attribute__((ext_vector_type(8))) short bf16x8;
typedef __attribute__((ext_vector_type(4))) float f32x4;
typedef __hip_bfloat16 bf16;

#define ASG(p) (const __attribute__((address_space(1))) void*)(p)
#define ASL(p) (__attribute__((address_space(3))) void*)(p)

// ---------------- small utility kernels ----------------

__global__ void k_zero(double* p, int n) {
    int i = blockIdx.x * 256 + threadIdx.x;
    if (i < n) p[i] = 0.0;
}

__global__ void k_cvt(const float* __restrict__ in, bf16* __restrict__ out, int n) {
    int i = blockIdx.x * 256 + threadIdx.x;
    if (i < n) out[i] = __float2bfloat16(in[i]);   // 0.0/1.0 -> exact
}

// Build BT[n][k2] (row-major [Npad x 2K]) from W [K x N] row-major.
// Limb-interleaved K2: k2 -> kt2 = k2>>6, kk = k2&63; limb = kt2&1,
// source k = (kt2>>1)*64 + kk. limb0 = hi(max(W,0)), limb1 = w - hi.
__global__ void k_limbs(const float* __restrict__ W, bf16* __restrict__ BT,
                        int K, int N, int Npad) {
    int idx = blockIdx.x * 256 + threadIdx.x;
    int total = Npad * 2 * K;
    if (idx >= total) return;
    int n  = idx / (2 * K);
    int k2 = idx - n * (2 * K);
    int kt2 = k2 >> 6;
    int kk  = k2 & 63;
    int k   = ((kt2 >> 1) << 6) + kk;
    float v = 0.f;
    if (n < N) {
        float w = fmaxf(W[(size_t)k * N + n], 0.f);      // Dale's law clamp
        float hi = __bfloat162float(__float2bfloat16(w));
        v = ((kt2 & 1) == 0) ? w : (w - hi);
    }
    BT[idx] = __float2bfloat16(v);
}

// ---------------- GEMM: C[M x ldc] = A[M x KA] @ BT^T, bf16 in, f32 out ----
// BT is [Npad x K2], limb-interleaved: k-iteration kt uses A k-tile (kt>>1).
// 128x128 tile, BK=64, 4 waves (2x2), 4x4 16x16x32 frags per wave.
// Staging via global_load_lds width=16 (linear LDS, per-lane global addr).
// A staged only on even kt. Store only cols < ldc.

__global__ __launch_bounds__(256) void k_gemm(
    const bf16* __restrict__ A, const bf16* __restrict__ BT,
    float* __restrict__ C, int KA, int K2, int ldc) {
    __shared__ __align__(16) short Alds[128 * 64];
    __shared__ __align__(16) short Blds[128 * 64];
    const int m0 = blockIdx.x * 128;
    const int n0 = blockIdx.y * 128;
    const int tid  = threadIdx.x;
    const int lane = tid & 63;
    const int wave = tid >> 6;
    const int wbase = wave * 64;          // lane-uniform within wave
    const int wm = (wave >> 1) * 64;
    const int wn = (wave & 1) * 64;
    const int r16 = lane & 15;
    const int kg  = lane >> 4;
    f32x4 acc[4][4] = {};
    const int nkt = K2 >> 6;
    for (int kt = 0; kt < nkt; ++kt) {
        const int kB0 = kt << 6;
        const int kA0 = (kt >> 1) << 6;
        __syncthreads();
        // stage tiles: 1024 x 16B each; global_load_lds, 16B/lane
#pragma unroll
        for (int r = 0; r < 4; ++r) {
            int idx = r * 256 + wbase + lane;   // 16B unit within tile
            int row = idx >> 3;
            int c8  = (idx & 7) << 3;
            if ((kt & 1) == 0)
                __builtin_amdgcn_global_load_lds(
                    ASG(&A[(size_t)(m0 + row) * KA + kA0 + c8]),
                    ASL(&Alds[(r * 256 + wbase) * 8]), 16, 0, 0);
            __builtin_amdgcn_global_load_lds(
                ASG(&BT[(size_t)(n0 + row) * K2 + kB0 + c8]),
                ASL(&Blds[(r * 256 + wbase) * 8]), 16, 0, 0);
        }
        __syncthreads();
#pragma unroll
        for (int kk = 0; kk < 2; ++kk) {
            bf16x8 af[4], bfr[4];
#pragma unroll
            for (int i = 0; i < 4; ++i) {
                af[i]  = *(const bf16x8*)&Alds[(wm + i * 16 + r16) * 64 + kk * 32 + kg * 8];
                bfr[i] = *(const bf16x8*)&Blds[(wn + i * 16 + r16) * 64 + kk * 32 + kg * 8];
            }
#pragma unroll
            for (int mi = 0; mi < 4; ++mi)
#pragma unroll
                for (int ni = 0; ni < 4; ++ni)
                    acc[mi][ni] = __builtin_amdgcn_mfma_f32_16x16x32_bf16(
                        af[mi], bfr[ni], acc[mi][ni], 0, 0, 0);
        }
    }
    // epilogue: D row = kg*4 + r, col = r16 (m89 mapping); store cols < ldc
#pragma unroll
    for (int mi = 0; mi < 4; ++mi)
#pragma unroll
        for (int ni = 0; ni < 4; ++ni) {
            int col = n0 + wn + ni * 16 + r16;
            if (col < ldc) {
#pragma unroll
                for (int r = 0; r < 4; ++r) {
                    int row = m0 + wm + mi * 16 + kg * 4 + r;
                    C[(size_t)row * ldc + col] = acc[mi][ni][r];
                }
            }
        }
}

// ---------------- LIF scan kernels (fp64 membranes, pipelined loads) -------

#define LIF_STEP(OFF, V)                                        \
    {                                                           \
        m = beta * m + (double)((V) + bj);                      \
        bool sp = (m >= 1.0);                                   \
        S[OFF] = sp ? one : zero;                               \
        m = sp ? 0.0 : m;                                       \
    }

// hidden layer: 16384 chains, 64-thread blocks (1 wave) x 256 blocks
__global__ __launch_bounds__(64) void k_scan_hidden(
    const float* __restrict__ I, const float* __restrict__ bias,
    double* __restrict__ mstate, bf16* __restrict__ S, int Tc, double beta) {
    int gid = blockIdx.x * 64 + threadIdx.x;
    int j = gid & (NH - 1);
    double m = mstate[gid];
    float bj = bias[j];
    const bf16 one  = __float2bfloat16(1.0f);
    const bf16 zero = __float2bfloat16(0.0f);
    const size_t stride = (size_t)NB * NH;       // per-t stride
    const float* Ip = I + gid;                   // gid = b*NH + j
    float bufA[8], bufB[8];
#pragma unroll
    for (int u = 0; u < 8; ++u) bufA[u] = Ip[(size_t)u * stride];
    for (int tb = 0; tb < Tc; tb += 16) {
#pragma unroll
        for (int u = 0; u < 8; ++u) bufB[u] = Ip[(size_t)(tb + 8 + u) * stride];
#pragma unroll
        for (int u = 0; u < 8; ++u) {
            size_t off = (size_t)(tb + u) * stride + gid;
            LIF_STEP(off, bufA[u]);
        }
        if (tb + 16 < Tc) {
#pragma unroll
            for (int u = 0; u < 8; ++u) bufA[u] = Ip[(size_t)(tb + 16 + u) * stride];
        }
#pragma unroll
        for (int u = 0; u < 8; ++u) {
            size_t off = (size_t)(tb + 8 + u) * stride + gid;
            LIF_STEP(off, bufB[u]);
        }
    }
    mstate[gid] = m;
}

// output layer: 256 chains (160 live), compact I2 [Mc x 16]
__global__ __launch_bounds__(256) void k_scan_out(
    const float* __restrict__ I2, const float* __restrict__ bias,
    double* __restrict__ mstate, float* __restrict__ out,
    int Tc, int t0, double beta) {
    int gid = threadIdx.x;
    int k = gid & 15;
    int b = gid >> 4;
    double m = mstate[gid];
    float bj = (k < N_OUT) ? bias[k] : 0.f;
    const float* Ip = I2 + gid;                  // I2[t*256 + gid]
    float bufA[8], bufB[8];
#pragma unroll
    for (int u = 0; u < 8; ++u) bufA[u] = Ip[(size_t)u * 256];
    for (int tb = 0; tb < Tc; tb += 16) {
#pragma unroll
        for (int u = 0; u < 8; ++u) bufB[u] = Ip[(size_t)(tb + 8 + u) * 256];
#pragma unroll
        for (int u = 0; u < 8; ++u) {
            int t = tb + u;
            m = beta * m + (double)(bufA[u] + bj);
            bool sp = (m >= 1.0);
            if (k < N_OUT) out[((size_t)(t0 + t) * NB + b) * N_OUT + k] = sp ? 1.f : 0.f;
            m = sp ? 0.0 : m;
        }
        if (tb + 16 < Tc) {
#pragma unroll
            for (int u = 0; u < 8; ++u) bufA[u] = Ip[(size_t)(tb + 16 + u) * 256];
        }
#pragma unroll
        for (int u = 0; u < 8; ++u) {
            int t = tb + 8 + u;
            m = beta * m + (double)(bufB[u] + bj);
            bool sp = (m >= 1.0);
            if (k < N_OUT) out[((size_t)(t0 + t) * NB + b) * N_OUT + k] = sp ? 1.f : 0.f;
            m = sp ? 0.0 : m;
        }
    }
    mstate[gid] = m;
}

// ---------------- host ----------------

extern "C" void kernel_launch(void* const* d_in, const int* in_sizes, int n_in,
                              void* d_out, int out_size, void* d_ws, size_t ws_size,
                              hipStream_t stream) {
    const float* in_sp = (const float*)d_in[0];
    const float* W0 = (const float*)d_in[1];
    const float* b0 = (const float*)d_in[2];
    const float* W1 = (const float*)d_in[3];
    const float* b1 = (const float*)d_in[4];
    const float* W2 = (const float*)d_in[5];
    const float* b2 = (const float*)d_in[6];
    float* out = (float*)d_out;

    char* p = (char*)d_ws;
    auto carve = [&](size_t bytes) -> void* {
        char* r = p; p += (bytes + 255) & ~(size_t)255; return (void*)r;
    };
    bf16* A_in = (bf16*)carve((size_t)T_STEPS * NB * N_IN * 2);
    bf16* BT0  = (bf16*)carve((size_t)NH * 2 * N_IN * 2);
    bf16* BT1  = (bf16*)carve((size_t)NH * 2 * NH * 2);
    bf16* BT2  = (bf16*)carve((size_t)128 * 2 * NH * 2);
    double* m0s = (double*)carve((size_t)NB * NH * 8);
    double* m1s = (double*)carve((size_t)NB * NH * 8);
    double* m2s = (double*)carve((size_t)NB * 16 * 8);
    size_t fixed = (size_t)(p - (char*)d_ws);

    // time-chunk: Tc | 4000, Tc % 16 == 0 (scan pipeline), Mc % 128 == 0
    // S0/S1 share one buffer (S0 dead before scan1 writes S1).
    const int tc_opts[7] = {2000, 800, 400, 160, 80, 32, 16};
    int Tc = 16;
    for (int i = 0; i < 7; ++i) {
        size_t Mc_ = (size_t)tc_opts[i] * NB;
        size_t need = fixed
            + ((Mc_ * NH * 4 + 255) & ~(size_t)255)
            + ((Mc_ * 16 * 4 + 255) & ~(size_t)255)
            + ((Mc_ * NH * 2 + 255) & ~(size_t)255);
        if (need <= ws_size) { Tc = tc_opts[i]; break; }
    }
    size_t Mc = (size_t)Tc * NB;
    float* IBUF  = (float*)carve(Mc * NH * 4);
    float* I2BUF = (float*)carve(Mc * 16 * 4);
    bf16*  S     = (bf16*)carve(Mc * NH * 2);

    const double beta = exp(-0.25 / 10.0);

    int nM = NB * NH;
    k_zero<<<(nM + 255) / 256, 256, 0, stream>>>(m0s, nM);
    k_zero<<<(nM + 255) / 256, 256, 0, stream>>>(m1s, nM);
    k_zero<<<1, 256, 0, stream>>>(m2s, NB * 16);

    int nIn = T_STEPS * NB * N_IN;
    k_cvt<<<(nIn + 255) / 256, 256, 0, stream>>>(in_sp, A_in, nIn);

    k_limbs<<<(NH * 2 * N_IN + 255) / 256, 256, 0, stream>>>(W0, BT0, N_IN, NH, NH);
    k_limbs<<<(NH * 2 * NH + 255) / 256, 256, 0, stream>>>(W1, BT1, NH, NH, NH);
    k_limbs<<<(128 * 2 * NH + 255) / 256, 256, 0, stream>>>(W2, BT2, NH, N_OUT, 128);

    const int C = T_STEPS / Tc;
    for (int c = 0; c < C; ++c) {
        int t0 = c * Tc;
        const bf16* Ain_c = A_in + (size_t)t0 * NB * N_IN;
        dim3 g0((unsigned)(Mc / 128), NH / 128);
        dim3 g2((unsigned)(Mc / 128), 1);
        // layer 0
        k_gemm<<<g0, 256, 0, stream>>>(Ain_c, BT0, IBUF, N_IN, 2 * N_IN, NH);
        k_scan_hidden<<<(NB * NH) / 64, 64, 0, stream>>>(IBUF, b0, m0s, S, Tc, beta);
        // layer 1
        k_gemm<<<g0, 256, 0, stream>>>(S, BT1, IBUF, NH, 2 * NH, NH);
        k_scan_hidden<<<(NB * NH) / 64, 64, 0, stream>>>(IBUF, b1, m1s, S, Tc, beta);
        // layer 2 (compact 16-col C)
        k_gemm<<<g2, 256, 0, stream>>>(S, BT2, I2BUF, NH, 2 * NH, 16);
        k_scan_out<<<1, 256, 0, stream>>>(I2BUF, b2, m2s, out, Tc, t0, beta);
    }
}